// Round 11
// baseline (191.248 us; speedup 1.0000x reference)
//
#include <hip/hip_runtime.h>

#define N_NODES 50000
#define N_EDGES 400000
#define DIM 160
#define NB 64
#define CUTOFF 5.0f
#define LN_EPS 1e-5f
#define PI_F 3.14159265358979323846f

// Padded CSR: stride-64 slot list per destination node.
#define SLOT_STRIDE 64
// deg padded to one counter per 32B (2 per 64B line): halves line-level
// atomic serialization vs stride-4, while keeping total ws = 14.50 MiB
// (< 16 MiB cap; the stride-16 variant at 16.02 MiB faulted in round 4).
#define DEG_STRIDE 8

// Workspace (ints), total 3,800,272 ints = 14.50 MiB:
//   [0..15]     ew accumulator (float) + pad
//   degp[N*8]   32B-padded degree counters (1.6 MB)
//   pkt[64]     float4 per RBF bucket {center, 1/width, proj_w, 0}
//   pos4[N]     float4 per node
//   esrc[N*64]  padded CSR slots (12.8 MB)
#define WS_DEG   16
#define WS_PKT   (WS_DEG + N_NODES * DEG_STRIDE)   // 400016
#define WS_POS4  (WS_PKT + 4 * NB)                 // 400272 (byte 1601088, 16B aligned)
#define WS_ESRC  (WS_POS4 + 4 * N_NODES)           // 600272 (byte 2401088, 16B aligned)

// ---------------------------------------------------------------------------
// K0: prep. Zeroes ew + padded deg (two int4 per node), packs pos into
// float4 rows, packs RBF table into one float4 per bucket.
// ---------------------------------------------------------------------------
__global__ __launch_bounds__(256) void prep(
    const float* __restrict__ pos, const float* __restrict__ centers,
    const float* __restrict__ widths, const float* __restrict__ proj_w,
    int* __restrict__ degp, float4* __restrict__ pkt,
    float4* __restrict__ pos4, float* __restrict__ ew_accum)
{
    const int i = blockIdx.x * blockDim.x + threadIdx.x;
    if (i < 16) ((int*)ew_accum)[i] = 0;
    if (i < NB)
        pkt[i] = make_float4(centers[i], 1.0f / widths[i], proj_w[i], 0.0f);
    if (i < N_NODES) {
        const int4 z4 = make_int4(0, 0, 0, 0);
        ((int4*)(degp))[2 * i]     = z4;
        ((int4*)(degp))[2 * i + 1] = z4;
        pos4[i] = make_float4(pos[3 * i], pos[3 * i + 1], pos[3 * i + 2], 0.0f);
    }
}

// ---------------------------------------------------------------------------
// K1: hist_ew_fill (EPT=4, 32B-padded counters).
// ---------------------------------------------------------------------------
#define EPT 4

__global__ __launch_bounds__(256) void hist_ew_fill(
    const int* __restrict__ ei, const float4* __restrict__ pos4,
    const float4* __restrict__ pkt, const float* __restrict__ proj_b,
    int* __restrict__ degp, int* __restrict__ esrc, float* __restrict__ ew_accum)
{
    const float bias = proj_b[0];
    const int base = blockIdx.x * (256 * EPT) + threadIdx.x;

    int  s[EPT], d[EPT], slot[EPT];
    bool v[EPT];
    #pragma unroll
    for (int k = 0; k < EPT; ++k) {
        const int e = base + 256 * k;
        v[k] = (e < N_EDGES);
        s[k] = v[k] ? ei[e] : 0;
        d[k] = v[k] ? ei[N_EDGES + e] : 0;
    }

    #pragma unroll
    for (int k = 0; k < EPT; ++k)
        slot[k] = v[k] ? atomicAdd(&degp[(long)d[k] * DEG_STRIDE], 1) : 0;

    float4 ps[EPT], pd[EPT];
    #pragma unroll
    for (int k = 0; k < EPT; ++k) { ps[k] = pos4[s[k]]; pd[k] = pos4[d[k]]; }

    #pragma unroll
    for (int k = 0; k < EPT; ++k)
        if (v[k] && slot[k] < SLOT_STRIDE)
            esrc[((long)d[k] << 6) + slot[k]] = s[k];

    float dist[EPT];
    #pragma unroll
    for (int k = 0; k < EPT; ++k) {
        const float dx = ps[k].x - pd[k].x;
        const float dy = ps[k].y - pd[k].y;
        const float dz = ps[k].z - pd[k].z;
        dist[k] = sqrtf(dx * dx + dy * dy + dz * dz);
    }

    float z[EPT] = {0.f, 0.f, 0.f, 0.f};
    #pragma unroll 4
    for (int b = 0; b < NB; ++b) {
        const float4 t4 = pkt[b];
        #pragma unroll
        for (int k = 0; k < EPT; ++k) {
            const float t = (dist[k] - t4.x) * t4.y;
            z[k] = fmaf(__expf(-0.5f * t * t), t4.z, z[k]);
        }
    }

    float sig = 0.0f;
    #pragma unroll
    for (int k = 0; k < EPT; ++k) {
        if (v[k]) {
            const float cut = (dist[k] <= CUTOFF)
                            ? 0.5f * (__cosf(PI_F * dist[k] * (1.0f / CUTOFF)) + 1.0f)
                            : 0.0f;
            sig += 1.0f / (1.0f + __expf(-(z[k] * cut + bias)));
        }
    }

    #pragma unroll
    for (int off = 32; off > 0; off >>= 1) sig += __shfl_xor(sig, off);
    __shared__ float red[4];
    if ((threadIdx.x & 63) == 0) red[threadIdx.x >> 6] = sig;
    __syncthreads();
    if (threadIdx.x == 0)
        atomicAdd(ew_accum, red[0] + red[1] + red[2] + red[3]);
}

// ---------------------------------------------------------------------------
// K2: FUSED gather + transform, LOW-LDS (round-10 design, resubmitted with
// explicit __threadfence_block hardening). Block = 64 nodes.
//  Phase A: 4 waves x 16 nodes wave-per-node gather (pairs), rows -> out[].
//  Phase B: fence + barrier, then node_direct's channels; row reads are
//           L2-hot (written moments ago by this block, same XCD).
// LDS = 20,480 B -> ~5 blocks/CU, so the gather phase keeps the ~20 waves/CU
// that made the split gather fast (round-8's 62 KB tile was the fusion
// killer; round-9 proved the transform needs no row tile).
// In-place safety: each wave owns nodes 16w..16w+15 in BOTH phases; reads
// precede writes in wave program order; scalar writes cols 0..63, vector
// reads cols 64..159 (disjoint 64B lines).
// ---------------------------------------------------------------------------
#define TNODES 64

__global__ __launch_bounds__(256) void gather_node(
    const float* __restrict__ x, const int* __restrict__ degp,
    const int* __restrict__ esrc, float* __restrict__ out,
    const float* __restrict__ W0, const float* __restrict__ W1,
    const float* __restrict__ ln_gamma, const float* __restrict__ ln_beta,
    const float* __restrict__ ew_accum)
{
    __shared__ float sW0[64 * 64];
    __shared__ float sW1[32 * 32];

    const int t    = threadIdx.x;
    const int lane = t & 63;
    const int w    = t >> 6;                 // wave 0..3
    const int node0 = blockIdx.x * TNODES;

    // ---- stage weights to LDS (coalesced; overlaps with gather issue) ----
    {
        const float4* w04 = (const float4*)W0;   // 1024 float4
        float4* s04 = (float4*)sW0;
        #pragma unroll
        for (int i = 0; i < 4; ++i) s04[t + 256 * i] = w04[t + 256 * i];
        ((float4*)sW1)[t] = ((const float4*)W1)[t];
    }

    // ---- Phase A: gather (wave w owns nodes node0+16w..+15, in pairs) ----
    #pragma unroll 1
    for (int p = 0; p < 16; p += 2) {
        const int nlA = w * 16 + p;
        const int nlB = nlA + 1;
        const int nA  = node0 + nlA;
        const int nB  = node0 + nlB;
        const long nAc = (nA < N_NODES) ? nA : 0;
        const long nBc = (nB < N_NODES) ? nB : 0;

        const int svA  = esrc[(nAc << 6) + lane];
        const int svB  = esrc[(nBc << 6) + lane];
        const int cntA = (nA < N_NODES) ? min(degp[nAc * DEG_STRIDE], SLOT_STRIDE) : 0;
        const int cntB = (nB < N_NODES) ? min(degp[nBc * DEG_STRIDE], SLOT_STRIDE) : 0;

        float4 aA = make_float4(0.f, 0.f, 0.f, 0.f);
        float4 aB = make_float4(0.f, 0.f, 0.f, 0.f);

        #define GBODY(sv, cnt, acc)                                            \
        {                                                                      \
            int j = 0;                                                         \
            for (; j + 8 <= cnt; j += 8) {                                     \
                const int s0 = __shfl(sv, j);                                  \
                const int s1 = __shfl(sv, j + 1);                              \
                const int s2 = __shfl(sv, j + 2);                              \
                const int s3 = __shfl(sv, j + 3);                              \
                const int s4 = __shfl(sv, j + 4);                              \
                const int s5 = __shfl(sv, j + 5);                              \
                const int s6 = __shfl(sv, j + 6);                              \
                const int s7 = __shfl(sv, j + 7);                              \
                if (lane < 40) {                                               \
                    const float4 v0 = ((const float4*)(x + (long)s0 * DIM))[lane]; \
                    const float4 v1 = ((const float4*)(x + (long)s1 * DIM))[lane]; \
                    const float4 v2 = ((const float4*)(x + (long)s2 * DIM))[lane]; \
                    const float4 v3 = ((const float4*)(x + (long)s3 * DIM))[lane]; \
                    const float4 v4 = ((const float4*)(x + (long)s4 * DIM))[lane]; \
                    const float4 v5 = ((const float4*)(x + (long)s5 * DIM))[lane]; \
                    const float4 v6 = ((const float4*)(x + (long)s6 * DIM))[lane]; \
                    const float4 v7 = ((const float4*)(x + (long)s7 * DIM))[lane]; \
                    acc.x += ((v0.x + v1.x) + (v2.x + v3.x)) + ((v4.x + v5.x) + (v6.x + v7.x)); \
                    acc.y += ((v0.y + v1.y) + (v2.y + v3.y)) + ((v4.y + v5.y) + (v6.y + v7.y)); \
                    acc.z += ((v0.z + v1.z) + (v2.z + v3.z)) + ((v4.z + v5.z) + (v6.z + v7.z)); \
                    acc.w += ((v0.w + v1.w) + (v2.w + v3.w)) + ((v4.w + v5.w) + (v6.w + v7.w)); \
                }                                                              \
            }                                                                  \
            for (; j + 4 <= cnt; j += 4) {                                     \
                const int s0 = __shfl(sv, j);                                  \
                const int s1 = __shfl(sv, j + 1);                              \
                const int s2 = __shfl(sv, j + 2);                              \
                const int s3 = __shfl(sv, j + 3);                              \
                if (lane < 40) {                                               \
                    const float4 v0 = ((const float4*)(x + (long)s0 * DIM))[lane]; \
                    const float4 v1 = ((const float4*)(x + (long)s1 * DIM))[lane]; \
                    const float4 v2 = ((const float4*)(x + (long)s2 * DIM))[lane]; \
                    const float4 v3 = ((const float4*)(x + (long)s3 * DIM))[lane]; \
                    acc.x += (v0.x + v1.x) + (v2.x + v3.x);                    \
                    acc.y += (v0.y + v1.y) + (v2.y + v3.y);                    \
                    acc.z += (v0.z + v1.z) + (v2.z + v3.z);                    \
                    acc.w += (v0.w + v1.w) + (v2.w + v3.w);                    \
                }                                                              \
            }                                                                  \
            for (; j < cnt; ++j) {                                             \
                const int s0 = __shfl(sv, j);                                  \
                if (lane < 40) {                                               \
                    const float4 v0 = ((const float4*)(x + (long)s0 * DIM))[lane]; \
                    acc.x += v0.x; acc.y += v0.y; acc.z += v0.z; acc.w += v0.w; \
                }                                                              \
            }                                                                  \
        }
        GBODY(svA, cntA, aA)
        GBODY(svB, cntB, aB)
        #undef GBODY

        if (lane < 40) {
            if (nA < N_NODES) *(float4*)(out + (long)nA * DIM + 4 * lane) = aA;
            if (nB < N_NODES) *(float4*)(out + (long)nB * DIM + 4 * lane) = aB;
        }
    }

    __threadfence_block();   // make phase-A global writes explicitly visible
    __syncthreads();         // block-wide; rows now L2-hot on this XCD

    const float ew   = ew_accum[0] * (1.0f / 400000.0f);
    const float s_m0 = ew * 0.125f;                 // / sqrt(64)
    const float s_m1 = ew * 0.17677669529663687f;   // / sqrt(32)

    // ---------------- scalar channel (node-quad x output-quad) ----------------
    {
        const int q   = t >> 4;          // 0..15 node quad
        const int sub = t & 15;          // 0..15 output quad
        const int n0  = node0 + 4 * q;
        const float* r0 = out + (long)((n0 + 0 < N_NODES) ? n0 + 0 : 0) * DIM;
        const float* r1 = out + (long)((n0 + 1 < N_NODES) ? n0 + 1 : 0) * DIM;
        const float* r2 = out + (long)((n0 + 2 < N_NODES) ? n0 + 2 : 0) * DIM;
        const float* r3 = out + (long)((n0 + 3 < N_NODES) ? n0 + 3 : 0) * DIM;

        float acc[4][4];
        #pragma unroll
        for (int n = 0; n < 4; ++n)
            #pragma unroll
            for (int j = 0; j < 4; ++j) acc[n][j] = 0.0f;

        #pragma unroll 4
        for (int k0 = 0; k0 < 64; k0 += 4) {
            const float4 a0 = *(const float4*)(r0 + k0);   // quad-uniform, L2-hot
            const float4 a1 = *(const float4*)(r1 + k0);
            const float4 a2 = *(const float4*)(r2 + k0);
            const float4 a3 = *(const float4*)(r3 + k0);
            const float4 w0 = *(const float4*)(sW0 + (k0 + 0) * 64 + 4 * sub);
            const float4 w1 = *(const float4*)(sW0 + (k0 + 1) * 64 + 4 * sub);
            const float4 w2 = *(const float4*)(sW0 + (k0 + 2) * 64 + 4 * sub);
            const float4 w3 = *(const float4*)(sW0 + (k0 + 3) * 64 + 4 * sub);
            #define FMA4(A, av, wv) \
                A[0] = fmaf(av, wv.x, A[0]); A[1] = fmaf(av, wv.y, A[1]); \
                A[2] = fmaf(av, wv.z, A[2]); A[3] = fmaf(av, wv.w, A[3]);
            FMA4(acc[0], a0.x, w0) FMA4(acc[0], a0.y, w1) FMA4(acc[0], a0.z, w2) FMA4(acc[0], a0.w, w3)
            FMA4(acc[1], a1.x, w0) FMA4(acc[1], a1.y, w1) FMA4(acc[1], a1.z, w2) FMA4(acc[1], a1.w, w3)
            FMA4(acc[2], a2.x, w0) FMA4(acc[2], a2.y, w1) FMA4(acc[2], a2.z, w2) FMA4(acc[2], a2.w, w3)
            FMA4(acc[3], a3.x, w0) FMA4(acc[3], a3.y, w1) FMA4(acc[3], a3.z, w2) FMA4(acc[3], a3.w, w3)
            #undef FMA4
        }

        float sum[4], ssq[4];
        #pragma unroll
        for (int n = 0; n < 4; ++n) {
            sum[n] = 0.0f; ssq[n] = 0.0f;
            #pragma unroll
            for (int j = 0; j < 4; ++j) {
                acc[n][j] *= s_m0;
                sum[n] += acc[n][j];
                ssq[n] = fmaf(acc[n][j], acc[n][j], ssq[n]);
            }
        }
        #pragma unroll
        for (int m = 1; m <= 8; m <<= 1) {
            #pragma unroll
            for (int n = 0; n < 4; ++n) {
                sum[n] += __shfl_xor(sum[n], m);
                ssq[n] += __shfl_xor(ssq[n], m);
            }
        }

        const float4 g = *(const float4*)(ln_gamma + 4 * sub);
        const float4 b = *(const float4*)(ln_beta  + 4 * sub);
        #pragma unroll
        for (int n = 0; n < 4; ++n) {
            const int node = node0 + 4 * q + n;
            if (node < N_NODES) {
                const float mu   = sum[n] * (1.0f / 64.0f);
                const float var  = ssq[n] * (1.0f / 64.0f) - mu * mu;
                const float rstd = rsqrtf(var + LN_EPS);
                const float t0 = (acc[n][0] - mu) * rstd * g.x + b.x;
                const float t1 = (acc[n][1] - mu) * rstd * g.y + b.y;
                const float t2 = (acc[n][2] - mu) * rstd * g.z + b.z;
                const float t3 = (acc[n][3] - mu) * rstd * g.w + b.w;
                float4 o;
                o.x = t0 / (1.0f + __expf(-t0));
                o.y = t1 / (1.0f + __expf(-t1));
                o.z = t2 / (1.0f + __expf(-t2));
                o.w = t3 / (1.0f + __expf(-t3));
                *(float4*)(out + (long)node * DIM + 4 * sub) = o;
            }
        }
    }

    // ---------------- vector channel (rows L2-hot, 4-lane bcast) -------------
    {
        const int nl   = t >> 2;          // 0..63 node within tile
        const int sub  = t & 3;           // c8
        const int node = node0 + nl;
        const bool valid = node < N_NODES;
        float* grow = out + (long)(valid ? node : 0) * DIM;
        const float* bRow = grow + 64;

        float o[24];
        #pragma unroll
        for (int m = 0; m < 24; ++m) o[m] = 0.0f;

        #pragma unroll 2
        for (int tt = 0; tt < 8; ++tt) {            // cp = 4tt + r
            const float4 v0 = *(const float4*)(bRow + 12 * tt);
            const float4 v1 = *(const float4*)(bRow + 12 * tt + 4);
            const float4 v2 = *(const float4*)(bRow + 12 * tt + 8);
            const float a[12] = { v0.x, v0.y, v0.z, v0.w,
                                  v1.x, v1.y, v1.z, v1.w,
                                  v2.x, v2.y, v2.z, v2.w };
            #pragma unroll
            for (int r = 0; r < 4; ++r) {
                const int cp = 4 * tt + r;
                const float a0 = a[3 * r];
                const float a1 = a[3 * r + 1];
                const float a2 = a[3 * r + 2];
                const float4* w4 = (const float4*)(sW1 + cp * 32 + sub * 8);
                const float4 wA = w4[0];
                const float4 wB = w4[1];
                const float wc[8] = { wA.x, wA.y, wA.z, wA.w, wB.x, wB.y, wB.z, wB.w };
                #pragma unroll
                for (int cc = 0; cc < 8; ++cc) {
                    o[3 * cc]     = fmaf(wc[cc], a0, o[3 * cc]);
                    o[3 * cc + 1] = fmaf(wc[cc], a1, o[3 * cc + 1]);
                    o[3 * cc + 2] = fmaf(wc[cc], a2, o[3 * cc + 2]);
                }
            }
        }

        if (valid) {
            float4* ro4 = (float4*)(grow + 64 + 24 * sub);
            #pragma unroll
            for (int q2 = 0; q2 < 6; ++q2) {
                float4 ov;
                ov.x = o[4 * q2]     * s_m1;
                ov.y = o[4 * q2 + 1] * s_m1;
                ov.z = o[4 * q2 + 2] * s_m1;
                ov.w = o[4 * q2 + 3] * s_m1;
                ro4[q2] = ov;
            }
        }
    }
}

extern "C" void kernel_launch(void* const* d_in, const int* in_sizes, int n_in,
                              void* d_out, int out_size, void* d_ws, size_t ws_size,
                              hipStream_t stream) {
    const float* x       = (const float*)d_in[0];
    const float* pos     = (const float*)d_in[1];
    const int*   ei      = (const int*)d_in[2];
    const float* W0      = (const float*)d_in[4];
    const float* W1      = (const float*)d_in[5];
    const float* centers = (const float*)d_in[6];
    const float* widths  = (const float*)d_in[7];
    const float* proj_w  = (const float*)d_in[8];
    const float* proj_b  = (const float*)d_in[9];
    const float* gamma   = (const float*)d_in[10];
    const float* beta    = (const float*)d_in[11];

    float* out  = (float*)d_out;
    int*   wsi  = (int*)d_ws;
    float* ew   = (float*)d_ws;
    int*   degp = wsi + WS_DEG;
    float4* pkt  = (float4*)(wsi + WS_PKT);
    float4* pos4 = (float4*)(wsi + WS_POS4);
    int*   esrc = wsi + WS_ESRC;

    const int pb = (N_NODES + 255) / 256;
    prep<<<pb, 256, 0, stream>>>(pos, centers, widths, proj_w, degp, pkt, pos4, ew);

    const int eb = (N_EDGES + 256 * EPT - 1) / (256 * EPT);   // 391
    hist_ew_fill<<<eb, 256, 0, stream>>>(ei, pos4, pkt, proj_b, degp, esrc, ew);

    const int tiles = (N_NODES + TNODES - 1) / TNODES;   // 782
    gather_node<<<tiles, 256, 0, stream>>>(x, degp, esrc, out,
                                           W0, W1, gamma, beta, ew);
}

// Round 12
// 186.017 us; speedup vs baseline: 1.0281x; 1.0281x over previous
//
#include <hip/hip_runtime.h>

#define N_NODES 50000
#define N_EDGES 400000
#define DIM 160
#define NB 64
#define CUTOFF 5.0f
#define LN_EPS 1e-5f
#define PI_F 3.14159265358979323846f

// Padded CSR: stride-64 slot list per destination node.
#define SLOT_STRIDE 64
// deg padded to one counter per 32B (2 per 64B line).
#define DEG_STRIDE 8

// Workspace (ints), total 3,800,272 ints = 14.50 MiB:
#define WS_DEG   16
#define WS_PKT   (WS_DEG + N_NODES * DEG_STRIDE)   // 400016
#define WS_POS4  (WS_PKT + 4 * NB)                 // 400272
#define WS_ESRC  (WS_POS4 + 4 * N_NODES)           // 600272

// ---------------------------------------------------------------------------
// K0: prep (unchanged).
// ---------------------------------------------------------------------------
__global__ __launch_bounds__(256) void prep(
    const float* __restrict__ pos, const float* __restrict__ centers,
    const float* __restrict__ widths, const float* __restrict__ proj_w,
    int* __restrict__ degp, float4* __restrict__ pkt,
    float4* __restrict__ pos4, float* __restrict__ ew_accum)
{
    const int i = blockIdx.x * blockDim.x + threadIdx.x;
    if (i < 16) ((int*)ew_accum)[i] = 0;
    if (i < NB)
        pkt[i] = make_float4(centers[i], 1.0f / widths[i], proj_w[i], 0.0f);
    if (i < N_NODES) {
        const int4 z4 = make_int4(0, 0, 0, 0);
        ((int4*)(degp))[2 * i]     = z4;
        ((int4*)(degp))[2 * i + 1] = z4;
        pos4[i] = make_float4(pos[3 * i], pos[3 * i + 1], pos[3 * i + 2], 0.0f);
    }
}

// ---------------------------------------------------------------------------
// K1: hist_ew_fill (unchanged).
// ---------------------------------------------------------------------------
#define EPT 4

__global__ __launch_bounds__(256) void hist_ew_fill(
    const int* __restrict__ ei, const float4* __restrict__ pos4,
    const float4* __restrict__ pkt, const float* __restrict__ proj_b,
    int* __restrict__ degp, int* __restrict__ esrc, float* __restrict__ ew_accum)
{
    const float bias = proj_b[0];
    const int base = blockIdx.x * (256 * EPT) + threadIdx.x;

    int  s[EPT], d[EPT], slot[EPT];
    bool v[EPT];
    #pragma unroll
    for (int k = 0; k < EPT; ++k) {
        const int e = base + 256 * k;
        v[k] = (e < N_EDGES);
        s[k] = v[k] ? ei[e] : 0;
        d[k] = v[k] ? ei[N_EDGES + e] : 0;
    }

    #pragma unroll
    for (int k = 0; k < EPT; ++k)
        slot[k] = v[k] ? atomicAdd(&degp[(long)d[k] * DEG_STRIDE], 1) : 0;

    float4 ps[EPT], pd[EPT];
    #pragma unroll
    for (int k = 0; k < EPT; ++k) { ps[k] = pos4[s[k]]; pd[k] = pos4[d[k]]; }

    #pragma unroll
    for (int k = 0; k < EPT; ++k)
        if (v[k] && slot[k] < SLOT_STRIDE)
            esrc[((long)d[k] << 6) + slot[k]] = s[k];

    float dist[EPT];
    #pragma unroll
    for (int k = 0; k < EPT; ++k) {
        const float dx = ps[k].x - pd[k].x;
        const float dy = ps[k].y - pd[k].y;
        const float dz = ps[k].z - pd[k].z;
        dist[k] = sqrtf(dx * dx + dy * dy + dz * dz);
    }

    float z[EPT] = {0.f, 0.f, 0.f, 0.f};
    #pragma unroll 4
    for (int b = 0; b < NB; ++b) {
        const float4 t4 = pkt[b];
        #pragma unroll
        for (int k = 0; k < EPT; ++k) {
            const float t = (dist[k] - t4.x) * t4.y;
            z[k] = fmaf(__expf(-0.5f * t * t), t4.z, z[k]);
        }
    }

    float sig = 0.0f;
    #pragma unroll
    for (int k = 0; k < EPT; ++k) {
        if (v[k]) {
            const float cut = (dist[k] <= CUTOFF)
                            ? 0.5f * (__cosf(PI_F * dist[k] * (1.0f / CUTOFF)) + 1.0f)
                            : 0.0f;
            sig += 1.0f / (1.0f + __expf(-(z[k] * cut + bias)));
        }
    }

    #pragma unroll
    for (int off = 32; off > 0; off >>= 1) sig += __shfl_xor(sig, off);
    __shared__ float red[4];
    if ((threadIdx.x & 63) == 0) red[threadIdx.x >> 6] = sig;
    __syncthreads();
    if (threadIdx.x == 0)
        atomicAdd(ew_accum, red[0] + red[1] + red[2] + red[3]);
}

// ---------------------------------------------------------------------------
// K2: FUSED gather + transform, SMALL-TILE variant. Round-11 found the fused
// kernel grid-starved (782 blocks -> 27% occupancy -> gather at 2.8 TB/s).
// TNODES=16 -> 3125 blocks (12 blocks/CU demand vs the 8-block LDS cap):
// full wave occupancy for the gather phase + continuous block turnover so
// late blocks' gather overlaps early blocks' transform.
//  Phase A: 4 waves x 4 nodes wave-per-node gather (pairs), rows -> out[].
//  Phase B: fence+barrier; scalar = (node, out-quad) w/ broadcast row reads
//           + 16-lane LN reduce; vector = (node, channel-pair) w/ float2 W1.
// LDS = 20,480 B. In-place safety: wave owns its nodes in both phases;
// scalar writes cols 0..63, vector reads/writes cols 64..159 (disjoint).
// ---------------------------------------------------------------------------
#define TNODES 16

__global__ __launch_bounds__(256) void gather_node(
    const float* __restrict__ x, const int* __restrict__ degp,
    const int* __restrict__ esrc, float* __restrict__ out,
    const float* __restrict__ W0, const float* __restrict__ W1,
    const float* __restrict__ ln_gamma, const float* __restrict__ ln_beta,
    const float* __restrict__ ew_accum)
{
    __shared__ float sW0[64 * 64];
    __shared__ float sW1[32 * 32];

    const int t    = threadIdx.x;
    const int lane = t & 63;
    const int w    = t >> 6;                 // wave 0..3
    const int node0 = blockIdx.x * TNODES;

    // ---- stage weights to LDS (coalesced; overlaps with gather issue) ----
    {
        const float4* w04 = (const float4*)W0;   // 1024 float4
        float4* s04 = (float4*)sW0;
        #pragma unroll
        for (int i = 0; i < 4; ++i) s04[t + 256 * i] = w04[t + 256 * i];
        ((float4*)sW1)[t] = ((const float4*)W1)[t];
    }

    // ---- Phase A: gather (wave w owns nodes node0+4w .. +3, in pairs) ----
    #pragma unroll 1
    for (int p = 0; p < 4; p += 2) {
        const int nlA = 4 * w + p;
        const int nlB = nlA + 1;
        const int nA  = node0 + nlA;
        const int nB  = node0 + nlB;
        const long nAc = (nA < N_NODES) ? nA : 0;
        const long nBc = (nB < N_NODES) ? nB : 0;

        const int svA  = esrc[(nAc << 6) + lane];
        const int svB  = esrc[(nBc << 6) + lane];
        const int cntA = (nA < N_NODES) ? min(degp[nAc * DEG_STRIDE], SLOT_STRIDE) : 0;
        const int cntB = (nB < N_NODES) ? min(degp[nBc * DEG_STRIDE], SLOT_STRIDE) : 0;

        float4 aA = make_float4(0.f, 0.f, 0.f, 0.f);
        float4 aB = make_float4(0.f, 0.f, 0.f, 0.f);

        #define GBODY(sv, cnt, acc)                                            \
        {                                                                      \
            int j = 0;                                                         \
            for (; j + 8 <= cnt; j += 8) {                                     \
                const int s0 = __shfl(sv, j);                                  \
                const int s1 = __shfl(sv, j + 1);                              \
                const int s2 = __shfl(sv, j + 2);                              \
                const int s3 = __shfl(sv, j + 3);                              \
                const int s4 = __shfl(sv, j + 4);                              \
                const int s5 = __shfl(sv, j + 5);                              \
                const int s6 = __shfl(sv, j + 6);                              \
                const int s7 = __shfl(sv, j + 7);                              \
                if (lane < 40) {                                               \
                    const float4 v0 = ((const float4*)(x + (long)s0 * DIM))[lane]; \
                    const float4 v1 = ((const float4*)(x + (long)s1 * DIM))[lane]; \
                    const float4 v2 = ((const float4*)(x + (long)s2 * DIM))[lane]; \
                    const float4 v3 = ((const float4*)(x + (long)s3 * DIM))[lane]; \
                    const float4 v4 = ((const float4*)(x + (long)s4 * DIM))[lane]; \
                    const float4 v5 = ((const float4*)(x + (long)s5 * DIM))[lane]; \
                    const float4 v6 = ((const float4*)(x + (long)s6 * DIM))[lane]; \
                    const float4 v7 = ((const float4*)(x + (long)s7 * DIM))[lane]; \
                    acc.x += ((v0.x + v1.x) + (v2.x + v3.x)) + ((v4.x + v5.x) + (v6.x + v7.x)); \
                    acc.y += ((v0.y + v1.y) + (v2.y + v3.y)) + ((v4.y + v5.y) + (v6.y + v7.y)); \
                    acc.z += ((v0.z + v1.z) + (v2.z + v3.z)) + ((v4.z + v5.z) + (v6.z + v7.z)); \
                    acc.w += ((v0.w + v1.w) + (v2.w + v3.w)) + ((v4.w + v5.w) + (v6.w + v7.w)); \
                }                                                              \
            }                                                                  \
            for (; j + 4 <= cnt; j += 4) {                                     \
                const int s0 = __shfl(sv, j);                                  \
                const int s1 = __shfl(sv, j + 1);                              \
                const int s2 = __shfl(sv, j + 2);                              \
                const int s3 = __shfl(sv, j + 3);                              \
                if (lane < 40) {                                               \
                    const float4 v0 = ((const float4*)(x + (long)s0 * DIM))[lane]; \
                    const float4 v1 = ((const float4*)(x + (long)s1 * DIM))[lane]; \
                    const float4 v2 = ((const float4*)(x + (long)s2 * DIM))[lane]; \
                    const float4 v3 = ((const float4*)(x + (long)s3 * DIM))[lane]; \
                    acc.x += (v0.x + v1.x) + (v2.x + v3.x);                    \
                    acc.y += (v0.y + v1.y) + (v2.y + v3.y);                    \
                    acc.z += (v0.z + v1.z) + (v2.z + v3.z);                    \
                    acc.w += (v0.w + v1.w) + (v2.w + v3.w);                    \
                }                                                              \
            }                                                                  \
            for (; j < cnt; ++j) {                                             \
                const int s0 = __shfl(sv, j);                                  \
                if (lane < 40) {                                               \
                    const float4 v0 = ((const float4*)(x + (long)s0 * DIM))[lane]; \
                    acc.x += v0.x; acc.y += v0.y; acc.z += v0.z; acc.w += v0.w; \
                }                                                              \
            }                                                                  \
        }
        GBODY(svA, cntA, aA)
        GBODY(svB, cntB, aB)
        #undef GBODY

        if (lane < 40) {
            if (nA < N_NODES) *(float4*)(out + (long)nA * DIM + 4 * lane) = aA;
            if (nB < N_NODES) *(float4*)(out + (long)nB * DIM + 4 * lane) = aB;
        }
    }

    __threadfence_block();
    __syncthreads();         // rows + weights visible; rows L2-hot this XCD

    const float ew   = ew_accum[0] * (1.0f / 400000.0f);
    const float s_m0 = ew * 0.125f;                 // / sqrt(64)
    const float s_m1 = ew * 0.17677669529663687f;   // / sqrt(32)

    const int nl  = t >> 4;          // 0..15 node within tile (4/wave)
    const int sub = t & 15;          // 0..15
    const int node = node0 + nl;
    const bool valid = node < N_NODES;
    float* grow = out + (long)(valid ? node : 0) * DIM;

    // ---------------- scalar channel: thread = (node, out-quad) --------------
    {
        float acc[4] = {0.f, 0.f, 0.f, 0.f};

        #pragma unroll 4
        for (int k0 = 0; k0 < 64; k0 += 4) {
            const float4 a = *(const float4*)(grow + k0);   // 16-lane broadcast
            const float4 w0 = *(const float4*)(sW0 + (k0 + 0) * 64 + 4 * sub);
            const float4 w1 = *(const float4*)(sW0 + (k0 + 1) * 64 + 4 * sub);
            const float4 w2 = *(const float4*)(sW0 + (k0 + 2) * 64 + 4 * sub);
            const float4 w3 = *(const float4*)(sW0 + (k0 + 3) * 64 + 4 * sub);
            acc[0] = fmaf(a.x, w0.x, fmaf(a.y, w1.x, fmaf(a.z, w2.x, fmaf(a.w, w3.x, acc[0]))));
            acc[1] = fmaf(a.x, w0.y, fmaf(a.y, w1.y, fmaf(a.z, w2.y, fmaf(a.w, w3.y, acc[1]))));
            acc[2] = fmaf(a.x, w0.z, fmaf(a.y, w1.z, fmaf(a.z, w2.z, fmaf(a.w, w3.z, acc[2]))));
            acc[3] = fmaf(a.x, w0.w, fmaf(a.y, w1.w, fmaf(a.z, w2.w, fmaf(a.w, w3.w, acc[3]))));
        }

        float sum = 0.0f, ssq = 0.0f;
        #pragma unroll
        for (int j = 0; j < 4; ++j) {
            acc[j] *= s_m0;
            sum += acc[j];
            ssq = fmaf(acc[j], acc[j], ssq);
        }
        // reduce across the 16-lane node group
        #pragma unroll
        for (int m = 1; m <= 8; m <<= 1) {
            sum += __shfl_xor(sum, m);
            ssq += __shfl_xor(ssq, m);
        }

        if (valid) {
            const float mu   = sum * (1.0f / 64.0f);
            const float var  = ssq * (1.0f / 64.0f) - mu * mu;
            const float rstd = rsqrtf(var + LN_EPS);
            const float4 g = *(const float4*)(ln_gamma + 4 * sub);
            const float4 b = *(const float4*)(ln_beta  + 4 * sub);
            const float t0 = (acc[0] - mu) * rstd * g.x + b.x;
            const float t1 = (acc[1] - mu) * rstd * g.y + b.y;
            const float t2 = (acc[2] - mu) * rstd * g.z + b.z;
            const float t3 = (acc[3] - mu) * rstd * g.w + b.w;
            float4 o;
            o.x = t0 / (1.0f + __expf(-t0));
            o.y = t1 / (1.0f + __expf(-t1));
            o.z = t2 / (1.0f + __expf(-t2));
            o.w = t3 / (1.0f + __expf(-t3));
            *(float4*)(grow + 4 * sub) = o;
        }
    }

    // ---------------- vector channel: thread = (node, channel-pair) ----------
    {
        const float* bRow = grow + 64;
        float o[6] = {0.f, 0.f, 0.f, 0.f, 0.f, 0.f};

        #pragma unroll 2
        for (int tt = 0; tt < 8; ++tt) {            // cp = 4tt + r
            const float4 v0 = *(const float4*)(bRow + 12 * tt);      // bcast
            const float4 v1 = *(const float4*)(bRow + 12 * tt + 4);
            const float4 v2 = *(const float4*)(bRow + 12 * tt + 8);
            const float a[12] = { v0.x, v0.y, v0.z, v0.w,
                                  v1.x, v1.y, v1.z, v1.w,
                                  v2.x, v2.y, v2.z, v2.w };
            #pragma unroll
            for (int r = 0; r < 4; ++r) {
                const int cp = 4 * tt + r;
                const float a0 = a[3 * r];
                const float a1 = a[3 * r + 1];
                const float a2 = a[3 * r + 2];
                const float2 wc = *(const float2*)(sW1 + cp * 32 + 2 * sub);
                o[0] = fmaf(wc.x, a0, o[0]);
                o[1] = fmaf(wc.x, a1, o[1]);
                o[2] = fmaf(wc.x, a2, o[2]);
                o[3] = fmaf(wc.y, a0, o[3]);
                o[4] = fmaf(wc.y, a1, o[4]);
                o[5] = fmaf(wc.y, a2, o[5]);
            }
        }

        if (valid) {
            float* vout = grow + 64 + 6 * sub;   // channels 2sub, 2sub+1
            float2* vo2 = (float2*)vout;         // 8B aligned (6*sub even)
            float2 p0, p1, p2;
            p0.x = o[0] * s_m1; p0.y = o[1] * s_m1;
            p1.x = o[2] * s_m1; p1.y = o[3] * s_m1;
            p2.x = o[4] * s_m1; p2.y = o[5] * s_m1;
            vo2[0] = p0; vo2[1] = p1; vo2[2] = p2;
        }
    }
}

extern "C" void kernel_launch(void* const* d_in, const int* in_sizes, int n_in,
                              void* d_out, int out_size, void* d_ws, size_t ws_size,
                              hipStream_t stream) {
    const float* x       = (const float*)d_in[0];
    const float* pos     = (const float*)d_in[1];
    const int*   ei      = (const int*)d_in[2];
    const float* W0      = (const float*)d_in[4];
    const float* W1      = (const float*)d_in[5];
    const float* centers = (const float*)d_in[6];
    const float* widths  = (const float*)d_in[7];
    const float* proj_w  = (const float*)d_in[8];
    const float* proj_b  = (const float*)d_in[9];
    const float* gamma   = (const float*)d_in[10];
    const float* beta    = (const float*)d_in[11];

    float* out  = (float*)d_out;
    int*   wsi  = (int*)d_ws;
    float* ew   = (float*)d_ws;
    int*   degp = wsi + WS_DEG;
    float4* pkt  = (float4*)(wsi + WS_PKT);
    float4* pos4 = (float4*)(wsi + WS_POS4);
    int*   esrc = wsi + WS_ESRC;

    const int pb = (N_NODES + 255) / 256;
    prep<<<pb, 256, 0, stream>>>(pos, centers, widths, proj_w, degp, pkt, pos4, ew);

    const int eb = (N_EDGES + 256 * EPT - 1) / (256 * EPT);   // 391
    hist_ew_fill<<<eb, 256, 0, stream>>>(ei, pos4, pkt, proj_b, degp, esrc, ew);

    const int tiles = (N_NODES + TNODES - 1) / TNODES;   // 3125
    gather_node<<<tiles, 256, 0, stream>>>(x, degp, esrc, out,
                                           W0, W1, gamma, beta, ew);
}

// Round 13
// 180.741 us; speedup vs baseline: 1.0581x; 1.0292x over previous
//
#include <hip/hip_runtime.h>

#define N_NODES 50000
#define N_EDGES 400000
#define DIM 160
#define NB 64
#define CUTOFF 5.0f
#define LN_EPS 1e-5f
#define PI_F 3.14159265358979323846f

// Padded CSR: stride-64 slot list per destination node.
#define SLOT_STRIDE 64
// deg padded to one counter per 32B (2 per 64B line).
#define DEG_STRIDE 8

// Workspace (ints), total 3,800,272 ints = 14.50 MiB:
#define WS_DEG   16
#define WS_PKT   (WS_DEG + N_NODES * DEG_STRIDE)   // 400016
#define WS_POS4  (WS_PKT + 4 * NB)                 // 400272
#define WS_ESRC  (WS_POS4 + 4 * N_NODES)           // 600272

// ---------------------------------------------------------------------------
// K0: prep (unchanged).
// ---------------------------------------------------------------------------
__global__ __launch_bounds__(256) void prep(
    const float* __restrict__ pos, const float* __restrict__ centers,
    const float* __restrict__ widths, const float* __restrict__ proj_w,
    int* __restrict__ degp, float4* __restrict__ pkt,
    float4* __restrict__ pos4, float* __restrict__ ew_accum)
{
    const int i = blockIdx.x * blockDim.x + threadIdx.x;
    if (i < 16) ((int*)ew_accum)[i] = 0;
    if (i < NB)
        pkt[i] = make_float4(centers[i], 1.0f / widths[i], proj_w[i], 0.0f);
    if (i < N_NODES) {
        const int4 z4 = make_int4(0, 0, 0, 0);
        ((int4*)(degp))[2 * i]     = z4;
        ((int4*)(degp))[2 * i + 1] = z4;
        pos4[i] = make_float4(pos[3 * i], pos[3 * i + 1], pos[3 * i + 2], 0.0f);
    }
}

// ---------------------------------------------------------------------------
// K1: hist_ew_fill (unchanged).
// ---------------------------------------------------------------------------
#define EPT 4

__global__ __launch_bounds__(256) void hist_ew_fill(
    const int* __restrict__ ei, const float4* __restrict__ pos4,
    const float4* __restrict__ pkt, const float* __restrict__ proj_b,
    int* __restrict__ degp, int* __restrict__ esrc, float* __restrict__ ew_accum)
{
    const float bias = proj_b[0];
    const int base = blockIdx.x * (256 * EPT) + threadIdx.x;

    int  s[EPT], d[EPT], slot[EPT];
    bool v[EPT];
    #pragma unroll
    for (int k = 0; k < EPT; ++k) {
        const int e = base + 256 * k;
        v[k] = (e < N_EDGES);
        s[k] = v[k] ? ei[e] : 0;
        d[k] = v[k] ? ei[N_EDGES + e] : 0;
    }

    #pragma unroll
    for (int k = 0; k < EPT; ++k)
        slot[k] = v[k] ? atomicAdd(&degp[(long)d[k] * DEG_STRIDE], 1) : 0;

    float4 ps[EPT], pd[EPT];
    #pragma unroll
    for (int k = 0; k < EPT; ++k) { ps[k] = pos4[s[k]]; pd[k] = pos4[d[k]]; }

    #pragma unroll
    for (int k = 0; k < EPT; ++k)
        if (v[k] && slot[k] < SLOT_STRIDE)
            esrc[((long)d[k] << 6) + slot[k]] = s[k];

    float dist[EPT];
    #pragma unroll
    for (int k = 0; k < EPT; ++k) {
        const float dx = ps[k].x - pd[k].x;
        const float dy = ps[k].y - pd[k].y;
        const float dz = ps[k].z - pd[k].z;
        dist[k] = sqrtf(dx * dx + dy * dy + dz * dz);
    }

    float z[EPT] = {0.f, 0.f, 0.f, 0.f};
    #pragma unroll 4
    for (int b = 0; b < NB; ++b) {
        const float4 t4 = pkt[b];
        #pragma unroll
        for (int k = 0; k < EPT; ++k) {
            const float t = (dist[k] - t4.x) * t4.y;
            z[k] = fmaf(__expf(-0.5f * t * t), t4.z, z[k]);
        }
    }

    float sig = 0.0f;
    #pragma unroll
    for (int k = 0; k < EPT; ++k) {
        if (v[k]) {
            const float cut = (dist[k] <= CUTOFF)
                            ? 0.5f * (__cosf(PI_F * dist[k] * (1.0f / CUTOFF)) + 1.0f)
                            : 0.0f;
            sig += 1.0f / (1.0f + __expf(-(z[k] * cut + bias)));
        }
    }

    #pragma unroll
    for (int off = 32; off > 0; off >>= 1) sig += __shfl_xor(sig, off);
    __shared__ float red[4];
    if ((threadIdx.x & 63) == 0) red[threadIdx.x >> 6] = sig;
    __syncthreads();
    if (threadIdx.x == 0)
        atomicAdd(ew_accum, red[0] + red[1] + red[2] + red[3]);
}

// ---------------------------------------------------------------------------
// K2: FUSED gather + transform, WAVE-PRIVATE LDS STAGING. Round-12 showed the
// kernel is traffic-bound at ~2.8 TB/s: the agg row round-trip through global
// (write 25 MB extra + re-read 32 MB + barrier convoy) is pure removable
// bytes, since the gathered row already sits in the wave's registers.
//  Per node pair: gather (registers) -> ds_write 2x160 floats to the wave's
//  private LDS slot -> transform IMMEDIATELY in-wave (no __syncthreads;
//  same-wave lgkmcnt orders ds_write->ds_read) -> write only the FINAL row.
//  Transform mapping: lanes 0-31 node A, 32-63 node B.
//   scalar: lane l -> outputs 2l,2l+1 (float2 W0 reads, 2-way/bank = free);
//           LN reduce = shfl_xor 1..16 within the 32-lane half.
//   vector: lane l -> channel l (b32 W1 reads, conflict-free).
// LDS = 20480 (weights) + 5120 (4 waves x 2 rows) = 25,600 B -> 6 blocks/CU.
// One barrier total (weight staging).
// ---------------------------------------------------------------------------
#define TNODES 16

__global__ __launch_bounds__(256) void gather_node(
    const float* __restrict__ x, const int* __restrict__ degp,
    const int* __restrict__ esrc, float* __restrict__ out,
    const float* __restrict__ W0, const float* __restrict__ W1,
    const float* __restrict__ ln_gamma, const float* __restrict__ ln_beta,
    const float* __restrict__ ew_accum)
{
    __shared__ float sW0[64 * 64];
    __shared__ float sW1[32 * 32];
    __shared__ float sRow[4][2][160];    // per-wave pair staging

    const int t    = threadIdx.x;
    const int lane = t & 63;
    const int w    = t >> 6;                 // wave 0..3
    const int node0 = blockIdx.x * TNODES;

    // ---- stage weights to LDS, single barrier ----
    {
        const float4* w04 = (const float4*)W0;   // 1024 float4
        float4* s04 = (float4*)sW0;
        #pragma unroll
        for (int i = 0; i < 4; ++i) s04[t + 256 * i] = w04[t + 256 * i];
        ((float4*)sW1)[t] = ((const float4*)W1)[t];
    }
    __syncthreads();

    const float ew   = ew_accum[0] * (1.0f / 400000.0f);
    const float s_m0 = ew * 0.125f;                 // / sqrt(64)
    const float s_m1 = ew * 0.17677669529663687f;   // / sqrt(32)

    const int half = lane >> 5;          // 0 = node A, 1 = node B
    const int l    = lane & 31;

    #pragma unroll 1
    for (int p = 0; p < 4; p += 2) {
        const int nA  = node0 + 4 * w + p;
        const int nB  = nA + 1;
        const long nAc = (nA < N_NODES) ? nA : 0;
        const long nBc = (nB < N_NODES) ? nB : 0;

        const int svA  = esrc[(nAc << 6) + lane];
        const int svB  = esrc[(nBc << 6) + lane];
        const int cntA = (nA < N_NODES) ? min(degp[nAc * DEG_STRIDE], SLOT_STRIDE) : 0;
        const int cntB = (nB < N_NODES) ? min(degp[nBc * DEG_STRIDE], SLOT_STRIDE) : 0;

        float4 aA = make_float4(0.f, 0.f, 0.f, 0.f);
        float4 aB = make_float4(0.f, 0.f, 0.f, 0.f);

        #define GBODY(sv, cnt, acc)                                            \
        {                                                                      \
            int j = 0;                                                         \
            for (; j + 8 <= cnt; j += 8) {                                     \
                const int s0 = __shfl(sv, j);                                  \
                const int s1 = __shfl(sv, j + 1);                              \
                const int s2 = __shfl(sv, j + 2);                              \
                const int s3 = __shfl(sv, j + 3);                              \
                const int s4 = __shfl(sv, j + 4);                              \
                const int s5 = __shfl(sv, j + 5);                              \
                const int s6 = __shfl(sv, j + 6);                              \
                const int s7 = __shfl(sv, j + 7);                              \
                if (lane < 40) {                                               \
                    const float4 v0 = ((const float4*)(x + (long)s0 * DIM))[lane]; \
                    const float4 v1 = ((const float4*)(x + (long)s1 * DIM))[lane]; \
                    const float4 v2 = ((const float4*)(x + (long)s2 * DIM))[lane]; \
                    const float4 v3 = ((const float4*)(x + (long)s3 * DIM))[lane]; \
                    const float4 v4 = ((const float4*)(x + (long)s4 * DIM))[lane]; \
                    const float4 v5 = ((const float4*)(x + (long)s5 * DIM))[lane]; \
                    const float4 v6 = ((const float4*)(x + (long)s6 * DIM))[lane]; \
                    const float4 v7 = ((const float4*)(x + (long)s7 * DIM))[lane]; \
                    acc.x += ((v0.x + v1.x) + (v2.x + v3.x)) + ((v4.x + v5.x) + (v6.x + v7.x)); \
                    acc.y += ((v0.y + v1.y) + (v2.y + v3.y)) + ((v4.y + v5.y) + (v6.y + v7.y)); \
                    acc.z += ((v0.z + v1.z) + (v2.z + v3.z)) + ((v4.z + v5.z) + (v6.z + v7.z)); \
                    acc.w += ((v0.w + v1.w) + (v2.w + v3.w)) + ((v4.w + v5.w) + (v6.w + v7.w)); \
                }                                                              \
            }                                                                  \
            for (; j + 4 <= cnt; j += 4) {                                     \
                const int s0 = __shfl(sv, j);                                  \
                const int s1 = __shfl(sv, j + 1);                              \
                const int s2 = __shfl(sv, j + 2);                              \
                const int s3 = __shfl(sv, j + 3);                              \
                if (lane < 40) {                                               \
                    const float4 v0 = ((const float4*)(x + (long)s0 * DIM))[lane]; \
                    const float4 v1 = ((const float4*)(x + (long)s1 * DIM))[lane]; \
                    const float4 v2 = ((const float4*)(x + (long)s2 * DIM))[lane]; \
                    const float4 v3 = ((const float4*)(x + (long)s3 * DIM))[lane]; \
                    acc.x += (v0.x + v1.x) + (v2.x + v3.x);                    \
                    acc.y += (v0.y + v1.y) + (v2.y + v3.y);                    \
                    acc.z += (v0.z + v1.z) + (v2.z + v3.z);                    \
                    acc.w += (v0.w + v1.w) + (v2.w + v3.w);                    \
                }                                                              \
            }                                                                  \
            for (; j < cnt; ++j) {                                             \
                const int s0 = __shfl(sv, j);                                  \
                if (lane < 40) {                                               \
                    const float4 v0 = ((const float4*)(x + (long)s0 * DIM))[lane]; \
                    acc.x += v0.x; acc.y += v0.y; acc.z += v0.z; acc.w += v0.w; \
                }                                                              \
            }                                                                  \
        }
        GBODY(svA, cntA, aA)
        GBODY(svB, cntB, aB)
        #undef GBODY

        // ---- stage the pair to this wave's private LDS slot ----
        if (lane < 40) {
            *(float4*)(&sRow[w][0][4 * lane]) = aA;
            *(float4*)(&sRow[w][1][4 * lane]) = aB;
        }
        // same-wave ds_write -> ds_read: compiler lgkmcnt orders; no barrier.

        const int  node  = node0 + 4 * w + p + half;
        const bool valid = node < N_NODES;
        float* grow = out + (long)(valid ? node : 0) * DIM;
        const float* row = &sRow[w][half][0];

        // ---------- scalar channel: lane -> outputs 2l, 2l+1 ----------
        {
            float a0 = 0.f, a1 = 0.f;
            #pragma unroll 4
            for (int k0 = 0; k0 < 64; k0 += 4) {
                const float4 a = *(const float4*)(row + k0);          // bcast
                const float2 q0 = *(const float2*)(sW0 + (k0 + 0) * 64 + 2 * l);
                const float2 q1 = *(const float2*)(sW0 + (k0 + 1) * 64 + 2 * l);
                const float2 q2 = *(const float2*)(sW0 + (k0 + 2) * 64 + 2 * l);
                const float2 q3 = *(const float2*)(sW0 + (k0 + 3) * 64 + 2 * l);
                a0 = fmaf(a.x, q0.x, fmaf(a.y, q1.x, fmaf(a.z, q2.x, fmaf(a.w, q3.x, a0))));
                a1 = fmaf(a.x, q0.y, fmaf(a.y, q1.y, fmaf(a.z, q2.y, fmaf(a.w, q3.y, a1))));
            }
            a0 *= s_m0;
            a1 *= s_m0;

            float sum = a0 + a1;
            float ssq = fmaf(a0, a0, a1 * a1);
            #pragma unroll
            for (int m = 1; m <= 16; m <<= 1) {       // within 32-lane half
                sum += __shfl_xor(sum, m);
                ssq += __shfl_xor(ssq, m);
            }

            if (valid) {
                const float mu   = sum * (1.0f / 64.0f);
                const float var  = ssq * (1.0f / 64.0f) - mu * mu;
                const float rstd = rsqrtf(var + LN_EPS);
                const float2 g = *(const float2*)(ln_gamma + 2 * l);
                const float2 b = *(const float2*)(ln_beta  + 2 * l);
                const float t0 = (a0 - mu) * rstd * g.x + b.x;
                const float t1 = (a1 - mu) * rstd * g.y + b.y;
                float2 o;
                o.x = t0 / (1.0f + __expf(-t0));
                o.y = t1 / (1.0f + __expf(-t1));
                *(float2*)(grow + 2 * l) = o;
            }
        }

        // ---------- vector channel: lane -> channel l ----------
        {
            const float* vrow = row + 64;
            float o0 = 0.f, o1 = 0.f, o2 = 0.f;
            #pragma unroll 2
            for (int g = 0; g < 8; ++g) {            // cp = 4g + r
                const float4 v0 = *(const float4*)(vrow + 12 * g);       // bcast
                const float4 v1 = *(const float4*)(vrow + 12 * g + 4);
                const float4 v2 = *(const float4*)(vrow + 12 * g + 8);
                const float a[12] = { v0.x, v0.y, v0.z, v0.w,
                                      v1.x, v1.y, v1.z, v1.w,
                                      v2.x, v2.y, v2.z, v2.w };
                #pragma unroll
                for (int r = 0; r < 4; ++r) {
                    const float wc = sW1[(4 * g + r) * 32 + l];   // conflict-free
                    o0 = fmaf(wc, a[3 * r],     o0);
                    o1 = fmaf(wc, a[3 * r + 1], o1);
                    o2 = fmaf(wc, a[3 * r + 2], o2);
                }
            }
            if (valid) {
                float* vo = grow + 64 + 3 * l;
                vo[0] = o0 * s_m1;
                vo[1] = o1 * s_m1;
                vo[2] = o2 * s_m1;
            }
        }
    }
}

extern "C" void kernel_launch(void* const* d_in, const int* in_sizes, int n_in,
                              void* d_out, int out_size, void* d_ws, size_t ws_size,
                              hipStream_t stream) {
    const float* x       = (const float*)d_in[0];
    const float* pos     = (const float*)d_in[1];
    const int*   ei      = (const int*)d_in[2];
    const float* W0      = (const float*)d_in[4];
    const float* W1      = (const float*)d_in[5];
    const float* centers = (const float*)d_in[6];
    const float* widths  = (const float*)d_in[7];
    const float* proj_w  = (const float*)d_in[8];
    const float* proj_b  = (const float*)d_in[9];
    const float* gamma   = (const float*)d_in[10];
    const float* beta    = (const float*)d_in[11];

    float* out  = (float*)d_out;
    int*   wsi  = (int*)d_ws;
    float* ew   = (float*)d_ws;
    int*   degp = wsi + WS_DEG;
    float4* pkt  = (float4*)(wsi + WS_PKT);
    float4* pos4 = (float4*)(wsi + WS_POS4);
    int*   esrc = wsi + WS_ESRC;

    const int pb = (N_NODES + 255) / 256;
    prep<<<pb, 256, 0, stream>>>(pos, centers, widths, proj_w, degp, pkt, pos4, ew);

    const int eb = (N_EDGES + 256 * EPT - 1) / (256 * EPT);   // 391
    hist_ew_fill<<<eb, 256, 0, stream>>>(ei, pos4, pkt, proj_b, degp, esrc, ew);

    const int tiles = (N_NODES + TNODES - 1) / TNODES;   // 3125
    gather_node<<<tiles, 256, 0, stream>>>(x, degp, esrc, out,
                                           W0, W1, gamma, beta, ew);
}